// Round 3
// baseline (992.632 us; speedup 1.0000x reference)
//
#include <hip/hip_runtime.h>
#include <cstdint>

#define NCLS 60
#define KC 512
#define DD 256
#define BB 32
#define NP 4096
#define LDP 260   // padded LDS row stride in floats (multiple of 4 for b128 alignment)

// Rounded fp32 multiply that cannot be fused into a following add (fma would
// change numerics vs numpy's separate mul+add in the SSE baseline path).
__device__ __forceinline__ float mul_rn_nofuse(float a, float b) {
  float p = a * b;
  asm volatile("" : "+v"(p));
  return p;
}

// numpy pairwise_sum of x*x over 256 contiguous floats:
// two 128-blocks (8-accumulator unroll each), halves added last.
__device__ __forceinline__ float np_pairwise256_sq(const float* row) {
  float h0 = 0.f, h1 = 0.f;
#pragma unroll
  for (int half = 0; half < 2; ++half) {
    const float* a = row + half * 128;
    float r[8];
#pragma unroll
    for (int j = 0; j < 8; ++j) r[j] = mul_rn_nofuse(a[j], a[j]);
    for (int blk = 1; blk < 16; ++blk) {
#pragma unroll
      for (int j = 0; j < 8; ++j) {
        float p = mul_rn_nofuse(a[blk * 8 + j], a[blk * 8 + j]);
        r[j] = r[j] + p;
      }
    }
    float res = ((r[0] + r[1]) + (r[2] + r[3])) + ((r[4] + r[5]) + (r[6] + r[7]));
    if (half == 0) h0 = res; else h1 = res;
  }
  return h0 + h1;
}

// ---- z_sq[b,n] = np.sum(z*z, -1) in numpy order (z_np[b,n,d] = z[b,d,n]) ----
__global__ __launch_bounds__(64) void zsq_kernel(const float* __restrict__ z,
                                                 float* __restrict__ zsq) {
  __shared__ float zs[64][LDP];
  int t = threadIdx.x;
  int b = blockIdx.x >> 6;            // 64 blocks per batch
  int n0 = (blockIdx.x & 63) * 64;
  const float* zb = z + (size_t)b * DD * NP;
  for (int d = 0; d < DD; ++d) zs[t][d] = zb[(size_t)d * NP + n0 + t];  // coalesced over n
  __syncthreads();
  zsq[b * NP + n0 + t] = np_pairwise256_sq(&zs[t][0]);
}

// ---- cb_sq[row] = np.sum(emb*emb, -1) for all 60*512 rows ----
__global__ __launch_bounds__(64) void cbsq_kernel(const float* __restrict__ emb,
                                                  float* __restrict__ cbsq) {
  __shared__ float cs[64][LDP];
  int t = threadIdx.x;
  int r0 = blockIdx.x * 64;
  const float4* e4 = (const float4*)emb;
  for (int rr = 0; rr < 64; ++rr) {
    float4 v = e4[(size_t)(r0 + rr) * 64 + t];   // one full row per iteration, coalesced
    *(float4*)&cs[rr][t * 4] = v;
  }
  __syncthreads();
  cbsq[r0 + t] = np_pairwise256_sq(&cs[t][0]);
}

// ---- main: dots in np-einsum SSE order, dist in fp32 np order, argmin first-min ----
__global__ __launch_bounds__(256, 2) void vq_main_kernel(
    const float* __restrict__ z, const int* __restrict__ c,
    const float* __restrict__ emb, const float* __restrict__ zsq,
    const float* __restrict__ cbsq, int* __restrict__ idx_out) {
  __shared__ float zs[32][LDP];
  __shared__ float cs[32][LDP];
  __shared__ float cbsq_s[32];
  const int t = threadIdx.x;
  const int b = blockIdx.y;
  const int n0 = blockIdx.x * 32;
  const int tk = t & 15, tn = t >> 4;
  const int cls = c[b];
  const float* zb = z + (size_t)b * DD * NP;
  const float* cb = emb + (size_t)cls * KC * DD;

  // stage z tile: 32 n-rows x 256 d
  {
    int nn = t & 31, dd = t >> 5;
    for (int it = 0; it < 32; ++it) {
      int d = it * 8 + dd;
      zs[nn][d] = zb[(size_t)d * NP + n0 + nn];
    }
  }
  float zsqv[2];
  zsqv[0] = zsq[b * NP + n0 + tn];
  zsqv[1] = zsq[b * NP + n0 + tn + 16];

  float m[2] = {3.4e38f, 3.4e38f};
  int bi[2] = {0, 0};

  for (int kt = 0; kt < 16; ++kt) {
    __syncthreads();   // previous tile fully consumed
    {   // stage cb tile: 32 k-rows x 256 d
      int r = t >> 3, cq = t & 7;
      const float4* e4 = (const float4*)(cb + (size_t)(kt * 32 + r) * DD);
      for (int it = 0; it < 8; ++it) {
        float4 v = e4[cq + it * 8];
        *(float4*)&cs[r][(cq + it * 8) * 4] = v;
      }
    }
    if (t < 32) cbsq_s[t] = cbsq[cls * KC + kt * 32 + t];
    __syncthreads();

    // 2x2 micro-tile: n-rows {tn, tn+16}, k-rows {tk, tk+16}
    // np einsum SSE path: 4 lane-accumulators, chunks of 16 with REVERSED
    // sub-block chain (s=3,2,1,0), separate mul+add (no fma).
    float A[2][2][4];
#pragma unroll
    for (int i = 0; i < 2; ++i)
#pragma unroll
      for (int j = 0; j < 2; ++j)
#pragma unroll
        for (int l = 0; l < 4; ++l) A[i][j][l] = 0.f;

    for (int t16 = 0; t16 < 16; ++t16) {
#pragma unroll
      for (int s = 3; s >= 0; --s) {
        int d0 = t16 * 16 + s * 4;
        float4 z0 = *(const float4*)&zs[tn][d0];
        float4 z1 = *(const float4*)&zs[tn + 16][d0];
        float4 c0 = *(const float4*)&cs[tk][d0];
        float4 c1 = *(const float4*)&cs[tk + 16][d0];
        float zz[2][4] = {{z0.x, z0.y, z0.z, z0.w}, {z1.x, z1.y, z1.z, z1.w}};
        float cc[2][4] = {{c0.x, c0.y, c0.z, c0.w}, {c1.x, c1.y, c1.z, c1.w}};
#pragma unroll
        for (int i = 0; i < 2; ++i)
#pragma unroll
          for (int j = 0; j < 2; ++j)
#pragma unroll
            for (int l = 0; l < 4; ++l) {
              float p = mul_rn_nofuse(zz[i][l], cc[j][l]);
              A[i][j][l] = p + A[i][j][l];
            }
      }
    }

    // npyv_sum (SSE3 hadd): (A0+A1)+(A2+A3); dist = (zsq - 2*dot) + cbsq
#pragma unroll
    for (int i = 0; i < 2; ++i)
#pragma unroll
      for (int j = 0; j < 2; ++j) {
        float dot = (A[i][j][0] + A[i][j][1]) + (A[i][j][2] + A[i][j][3]);
        float dist = (zsqv[i] - 2.0f * dot) + cbsq_s[tk + 16 * j];  // 2*dot exact
        int k = kt * 32 + tk + 16 * j;   // strictly ascending per thread
        if (dist < m[i]) { m[i] = dist; bi[i] = k; }
      }
  }

  // reduce across the 16 tk-lanes sharing each n (lex min on (value, index))
#pragma unroll
  for (int i = 0; i < 2; ++i) {
#pragma unroll
    for (int off = 8; off >= 1; off >>= 1) {
      float om = __shfl_xor(m[i], off);
      int oi = __shfl_xor(bi[i], off);
      if (om < m[i] || (om == m[i] && oi < bi[i])) { m[i] = om; bi[i] = oi; }
    }
    if (tk == 0) idx_out[b * NP + n0 + tn + 16 * i] = bi[i];
  }
}

// ---- gather selected rows -> [B,H,W,D] (bitwise copy of embedding rows) ----
__global__ __launch_bounds__(256) void vq_gather_kernel(
    const int* __restrict__ c, const float* __restrict__ emb,
    const int* __restrict__ idx, float* __restrict__ out) {
  int t = threadIdx.x;
  int r = blockIdx.x * 4 + (t >> 6);
  int lane = t & 63;
  int b = r >> 12;
  int k = idx[r];
  const float4* src = (const float4*)(emb + (size_t)(c[b] * KC + k) * DD);
  float4* dst = (float4*)(out + (size_t)r * DD);
  dst[lane] = src[lane];
}

extern "C" void kernel_launch(void* const* d_in, const int* in_sizes, int n_in,
                              void* d_out, int out_size, void* d_ws, size_t ws_size,
                              hipStream_t stream) {
  const float* z = (const float*)d_in[0];    // [32,256,64,64]
  const int* c = (const int*)d_in[1];        // [32]
  const float* emb = (const float*)d_in[2];  // [30720,256]
  float* out = (float*)d_out;                // [32,64,64,256]

  char* ws = (char*)d_ws;
  float* zsq = (float*)ws;                       // 131072 f32
  float* cbsq = (float*)(ws + 524288);           // 30720 f32
  int* idx = (int*)(ws + 524288 + 122880);       // 131072 i32

  zsq_kernel<<<BB * (NP / 64), 64, 0, stream>>>(z, zsq);
  cbsq_kernel<<<(NCLS * KC) / 64, 64, 0, stream>>>(emb, cbsq);
  dim3 gA(NP / 32, BB);
  vq_main_kernel<<<gA, 256, 0, stream>>>(z, c, emb, zsq, cbsq, idx);
  vq_gather_kernel<<<(BB * NP) / 4, 256, 0, stream>>>(c, emb, idx, out);
}